// Round 2
// baseline (3761.097 us; speedup 1.0000x reference)
//
#include <hip/hip_runtime.h>
#include <hip/hip_bf16.h>
#include <cstdint>
#include <cstddef>

#define H_     64
#define P_     64
#define G_     8
#define N_     128
#define K_     4
#define CS_    256
#define HID_   2048
#define INTER_ 4096
#define CONVD_ 6144
#define PROJ_  10304
#define DTOFF_ 10240   /* INTER_+CONVD_ */
#define B_     2
#define L_     2048
#define NC_    8
#define ML_    4096    /* B_*L_ */
#define EPS_   1e-5f

typedef unsigned short ushort_t;

__device__ inline float b2f(ushort_t v) {
  unsigned u = ((unsigned)v) << 16;
  float f;
  __builtin_memcpy(&f, &u, 4);
  return f;
}
__device__ inline ushort_t f2b(float f) {
  unsigned u;
  __builtin_memcpy(&u, &f, 4);
  u = u + 0x7FFFu + ((u >> 16) & 1u);   // round-to-nearest-even
  return (ushort_t)(u >> 16);
}
__device__ inline void ld_bf8(const ushort_t* p, float* f) {
  uint4 u = *(const uint4*)p;
  const ushort_t* s = (const ushort_t*)&u;
#pragma unroll
  for (int c = 0; c < 8; ++c) f[c] = b2f(s[c]);
}
__device__ inline void st_bf8(ushort_t* p, const float* f) {
  uint4 u;
  ushort_t* s = (ushort_t*)&u;
#pragma unroll
  for (int c = 0; c < 8; ++c) s[c] = f2b(f[c]);
  *(uint4*)p = u;
}

// ---------------------------------------------------------------------------
// GEMM1: C[m,n] = sum_k A[m,k]*B[n,k], fp32 inputs, bf16 output, plus fp32
// sidecar for the dt columns (n >= DTOFF_). 128x128 tile, BK=8, 256 thr.
// ---------------------------------------------------------------------------
__global__ __launch_bounds__(256) void gemm1_k(const float* __restrict__ A,
                                               const float* __restrict__ Bm,
                                               ushort_t* __restrict__ C,
                                               float* __restrict__ dtraw,
                                               int M, int N, int Kd) {
  __shared__ float As[8][132];
  __shared__ float Bs[8][132];
  int bm = blockIdx.y * 128, bn = blockIdx.x * 128;
  int t = threadIdx.x;
  int lr = t >> 1, lq = t & 1;
  int tx = t & 15, ty = t >> 4;
  float acc[8][8];
#pragma unroll
  for (int i = 0; i < 8; ++i)
#pragma unroll
    for (int j = 0; j < 8; ++j) acc[i][j] = 0.f;

  for (int k0 = 0; k0 < Kd; k0 += 8) {
    float4 av = make_float4(0.f, 0.f, 0.f, 0.f);
    float4 bv = make_float4(0.f, 0.f, 0.f, 0.f);
    int ar = bm + lr;
    if (ar < M) av = *(const float4*)(A + (size_t)ar * Kd + k0 + lq * 4);
    int br = bn + lr;
    if (br < N) bv = *(const float4*)(Bm + (size_t)br * Kd + k0 + lq * 4);
    __syncthreads();
    As[lq*4+0][lr] = av.x; As[lq*4+1][lr] = av.y; As[lq*4+2][lr] = av.z; As[lq*4+3][lr] = av.w;
    Bs[lq*4+0][lr] = bv.x; Bs[lq*4+1][lr] = bv.y; Bs[lq*4+2][lr] = bv.z; Bs[lq*4+3][lr] = bv.w;
    __syncthreads();
#pragma unroll
    for (int kk = 0; kk < 8; ++kk) {
      float a[8], b[8];
#pragma unroll
      for (int i = 0; i < 8; ++i) a[i] = As[kk][ty * 8 + i];
#pragma unroll
      for (int j = 0; j < 8; ++j) b[j] = Bs[kk][tx * 8 + j];
#pragma unroll
      for (int i = 0; i < 8; ++i)
#pragma unroll
        for (int j = 0; j < 8; ++j) acc[i][j] = fmaf(a[i], b[j], acc[i][j]);
    }
  }

  bool fullN = (bn + 128 <= N);
#pragma unroll
  for (int i = 0; i < 8; ++i) {
    int row = bm + ty * 8 + i;
    if (row >= M) continue;
    if (fullN) {
      st_bf8(C + (size_t)row * N + bn + tx * 8, acc[i]);
    } else {
#pragma unroll
      for (int j = 0; j < 8; ++j) {
        int col = bn + tx * 8 + j;
        if (col < N) {
          C[(size_t)row * N + col] = f2b(acc[i][j]);
          if (col >= DTOFF_) dtraw[(size_t)row * 64 + (col - DTOFF_)] = acc[i][j];
        }
      }
    }
  }
}

// ---------------------------------------------------------------------------
// GEMM2: bf16 A (Yb) x fp32 B (out_proj_w) -> fp32 C. M,N multiples of 128.
// ---------------------------------------------------------------------------
__global__ __launch_bounds__(256) void gemm2_k(const ushort_t* __restrict__ A,
                                               const float* __restrict__ Bm,
                                               float* __restrict__ C,
                                               int M, int N, int Kd) {
  __shared__ float As[8][132];
  __shared__ float Bs[8][132];
  int bm = blockIdx.y * 128, bn = blockIdx.x * 128;
  int t = threadIdx.x;
  int tx = t & 15, ty = t >> 4;
  float acc[8][8];
#pragma unroll
  for (int i = 0; i < 8; ++i)
#pragma unroll
    for (int j = 0; j < 8; ++j) acc[i][j] = 0.f;

  for (int k0 = 0; k0 < Kd; k0 += 8) {
    float av[8];
    float4 b0, b1;
    if (t < 128) {
      ld_bf8(A + (size_t)(bm + t) * Kd + k0, av);
    } else {
      int r = t - 128;
      b0 = *(const float4*)(Bm + (size_t)(bn + r) * Kd + k0);
      b1 = *(const float4*)(Bm + (size_t)(bn + r) * Kd + k0 + 4);
    }
    __syncthreads();
    if (t < 128) {
#pragma unroll
      for (int c = 0; c < 8; ++c) As[c][t] = av[c];
    } else {
      int r = t - 128;
      Bs[0][r] = b0.x; Bs[1][r] = b0.y; Bs[2][r] = b0.z; Bs[3][r] = b0.w;
      Bs[4][r] = b1.x; Bs[5][r] = b1.y; Bs[6][r] = b1.z; Bs[7][r] = b1.w;
    }
    __syncthreads();
#pragma unroll
    for (int kk = 0; kk < 8; ++kk) {
      float a[8], b[8];
#pragma unroll
      for (int i = 0; i < 8; ++i) a[i] = As[kk][ty * 8 + i];
#pragma unroll
      for (int j = 0; j < 8; ++j) b[j] = Bs[kk][tx * 8 + j];
#pragma unroll
      for (int i = 0; i < 8; ++i)
#pragma unroll
        for (int j = 0; j < 8; ++j) acc[i][j] = fmaf(a[i], b[j], acc[i][j]);
    }
  }

#pragma unroll
  for (int i = 0; i < 8; ++i) {
    int row = bm + ty * 8 + i;
    float* cp = C + (size_t)row * N + bn + tx * 8;
    *(float4*)cp       = make_float4(acc[i][0], acc[i][1], acc[i][2], acc[i][3]);
    *(float4*)(cp + 4) = make_float4(acc[i][4], acc[i][5], acc[i][6], acc[i][7]);
  }
}

// ---------------------------------------------------------------------------
// Causal depthwise conv (K=4) + SiLU, bf16 in (zb xBC slice) -> bf16 out.
// 8 channels per thread, vector loads.
// ---------------------------------------------------------------------------
__global__ __launch_bounds__(256) void conv_silu_k(const ushort_t* __restrict__ zb,
                                                   const float* __restrict__ cw,
                                                   const float* __restrict__ cb,
                                                   ushort_t* __restrict__ xcb) {
  int idx = blockIdx.x * 256 + threadIdx.x;     // ML_ * 768 units
  int c8 = (idx % 768) * 8;
  int row = idx / 768;
  int l = row % L_;
  float a[8];
#pragma unroll
  for (int c = 0; c < 8; ++c) a[c] = cb[c8 + c];
#pragma unroll
  for (int i = 0; i < K_; ++i) {
    int ll = l - (K_ - 1) + i;
    if (ll >= 0) {
      float xv[8];
      ld_bf8(zb + (size_t)(row - (K_ - 1) + i) * PROJ_ + INTER_ + c8, xv);
#pragma unroll
      for (int c = 0; c < 8; ++c) a[c] = fmaf(cw[(c8 + c) * K_ + i], xv[c], a[c]);
    }
  }
#pragma unroll
  for (int c = 0; c < 8; ++c) a[c] = a[c] / (1.f + __expf(-a[c]));
  st_bf8(xcb + (size_t)row * CONVD_ + c8, a);
}

// ---------------------------------------------------------------------------
// dt: softplus(dtraw + bias); dA = dt*A; inclusive cumsum per chunk (CS=256).
// One block per (b, chunk, head). fp32 throughout.
// ---------------------------------------------------------------------------
__global__ __launch_bounds__(256) void dt_scan_k(const float* __restrict__ dtraw,
                                                 const float* __restrict__ dt_bias,
                                                 const float* __restrict__ A_log,
                                                 float* __restrict__ dtp,
                                                 float* __restrict__ dacs,
                                                 float* __restrict__ cdec) {
  int bzh = blockIdx.x;
  int h = bzh & 63, z = (bzh >> 6) & 7, b = bzh >> 9;
  int i = threadIdx.x;
  size_t row = (size_t)b * L_ + z * CS_ + i;
  float dv = dtraw[row * 64 + h] + dt_bias[h];
  float sp = (dv > 20.f) ? dv : log1pf(expf(dv));
  float v = sp * (-expf(A_log[h]));
  __shared__ float sm[256];
  sm[i] = v;
  __syncthreads();
  for (int off = 1; off < 256; off <<= 1) {
    float add = (i >= off) ? sm[i - off] : 0.f;
    __syncthreads();
    sm[i] += add;
    __syncthreads();
  }
  float cs = sm[i];
  size_t ob = ((size_t)b * H_ + h) * L_ + z * CS_ + i;
  dtp[ob] = sp;
  dacs[ob] = cs;
  if (i == CS_ - 1) cdec[bzh] = expf(cs);
}

// ---------------------------------------------------------------------------
// CB[i,j] = sum_n C[i,n]*B[j,n], lower-triangular 64x64 tiles only. bf16 out.
// ---------------------------------------------------------------------------
__global__ __launch_bounds__(256) void cb_k(const ushort_t* __restrict__ xcb,
                                            ushort_t* __restrict__ CBo) {
  int jt = blockIdx.x & 3, it = blockIdx.x >> 2;
  if (jt > it) return;
  int bzg = blockIdx.y;
  int g = bzg & 7, z = (bzg >> 3) & 7, b = bzg >> 6;
  int t = threadIdx.x;
  int tx = t & 15, ty = t >> 4;
  __shared__ float CtT[64][68];   // [n_local][i_local]
  __shared__ float BtT[64][68];   // [n_local][j_local]
  size_t rowbase = (size_t)b * L_ + (size_t)z * CS_;
  float acc[4][4];
#pragma unroll
  for (int i = 0; i < 4; ++i)
#pragma unroll
    for (int j = 0; j < 4; ++j) acc[i][j] = 0.f;

  for (int half = 0; half < 2; ++half) {
    int nb = half * 64;
    __syncthreads();
#pragma unroll
    for (int u = 0; u < 2; ++u) {
      int idx = t + u * 256;            // 512 units of 8 bf16 = 64 rows x 8
      int rr = idx >> 3, f = idx & 7;
      float cv[8], bv[8];
      ld_bf8(xcb + (rowbase + it * 64 + rr) * CONVD_ + INTER_ + G_ * N_ + g * N_ + nb + f * 8, cv);
      ld_bf8(xcb + (rowbase + jt * 64 + rr) * CONVD_ + INTER_ + g * N_ + nb + f * 8, bv);
#pragma unroll
      for (int c = 0; c < 8; ++c) { CtT[f * 8 + c][rr] = cv[c]; BtT[f * 8 + c][rr] = bv[c]; }
    }
    __syncthreads();
    for (int n = 0; n < 64; ++n) {
      float4 cv = *(const float4*)&CtT[n][ty * 4];
      float4 bv = *(const float4*)&BtT[n][tx * 4];
      float cc[4] = {cv.x, cv.y, cv.z, cv.w};
      float bb[4] = {bv.x, bv.y, bv.z, bv.w};
#pragma unroll
      for (int i = 0; i < 4; ++i)
#pragma unroll
        for (int j = 0; j < 4; ++j) acc[i][j] = fmaf(cc[i], bb[j], acc[i][j]);
    }
  }
  size_t cbase = ((size_t)((b * 8 + z) * 8 + g)) * (CS_ * CS_);
#pragma unroll
  for (int i = 0; i < 4; ++i) {
    int row = it * 64 + ty * 4 + i;
    ushort4 v;
    v.x = f2b(acc[i][0]); v.y = f2b(acc[i][1]); v.z = f2b(acc[i][2]); v.w = f2b(acc[i][3]);
    *(ushort4*)(CBo + cbase + (size_t)row * CS_ + jt * 64 + tx * 4) = v;
  }
}

// ---------------------------------------------------------------------------
// Per-chunk states: S[p,n] = sum_j x[j,p]*w[j]*B[j,n]. fp32 out.
// ---------------------------------------------------------------------------
__global__ __launch_bounds__(256) void states_k(const ushort_t* __restrict__ xcb,
                                                const float* __restrict__ dacs,
                                                const float* __restrict__ dtp,
                                                float* __restrict__ st) {
  int bzh = blockIdx.x;
  int h = bzh & 63, z = (bzh >> 6) & 7, b = bzh >> 9;
  int g = h >> 3;
  int t = threadIdx.x;
  __shared__ float ws[256];
  __shared__ float xt[64][64];
  __shared__ float Bt[64][128];
  size_t base = ((size_t)b * H_ + h) * L_ + z * CS_;
  float dlast = dacs[base + CS_ - 1];
  ws[t] = __expf(dlast - dacs[base + t]) * dtp[base + t];
  int p0 = (t & 15) * 4, n0 = (t >> 4) * 8;
  float acc[4][8];
#pragma unroll
  for (int i = 0; i < 4; ++i)
#pragma unroll
    for (int j = 0; j < 8; ++j) acc[i][j] = 0.f;
  size_t rowbase = (size_t)b * L_ + z * CS_;

  for (int j0 = 0; j0 < CS_; j0 += 64) {
    __syncthreads();
#pragma unroll
    for (int u = 0; u < 2; ++u) {       // x: 64 rows x 8 units
      int idx = t + u * 256;
      int rr = idx >> 3, f = idx & 7;
      float xv[8];
      ld_bf8(xcb + (rowbase + j0 + rr) * CONVD_ + h * P_ + f * 8, xv);
#pragma unroll
      for (int c = 0; c < 8; ++c) xt[rr][f * 8 + c] = xv[c];
    }
#pragma unroll
    for (int u = 0; u < 4; ++u) {       // B: 64 rows x 16 units
      int idx = t + u * 256;
      int rr = idx >> 4, f = idx & 15;
      float bv[8];
      ld_bf8(xcb + (rowbase + j0 + rr) * CONVD_ + INTER_ + g * N_ + f * 8, bv);
#pragma unroll
      for (int c = 0; c < 8; ++c) Bt[rr][f * 8 + c] = bv[c];
    }
    __syncthreads();
    for (int jj = 0; jj < 64; ++jj) {
      float wj = ws[j0 + jj];
      float4 xv = *(const float4*)&xt[jj][p0];
      float xw[4] = {xv.x * wj, xv.y * wj, xv.z * wj, xv.w * wj};
      float4 b0v = *(const float4*)&Bt[jj][n0];
      float4 b1v = *(const float4*)&Bt[jj][n0 + 4];
      float bb[8] = {b0v.x, b0v.y, b0v.z, b0v.w, b1v.x, b1v.y, b1v.z, b1v.w};
#pragma unroll
      for (int pp = 0; pp < 4; ++pp)
#pragma unroll
        for (int nn = 0; nn < 8; ++nn) acc[pp][nn] = fmaf(xw[pp], bb[nn], acc[pp][nn]);
    }
  }
  float* outp = st + ((size_t)((b * 8 + z) * H_ + h)) * (P_ * N_);
#pragma unroll
  for (int pp = 0; pp < 4; ++pp) {
    *(float4*)(outp + (size_t)(p0 + pp) * N_ + n0) =
        make_float4(acc[pp][0], acc[pp][1], acc[pp][2], acc[pp][3]);
    *(float4*)(outp + (size_t)(p0 + pp) * N_ + n0 + 4) =
        make_float4(acc[pp][4], acc[pp][5], acc[pp][6], acc[pp][7]);
  }
}

// ---------------------------------------------------------------------------
// Inter-chunk exclusive scan over nc=8 chunks, IN PLACE on st:
// st[z] := prev state before chunk z.
// ---------------------------------------------------------------------------
__global__ __launch_bounds__(256) void scan_k(float* __restrict__ st,
                                              const float* __restrict__ cdec) {
  size_t idx = (size_t)blockIdx.x * 256 + threadIdx.x;
  int b = (int)(idx >> 19);            // 524288 = H_*P_*N_
  size_t rem = idx & 524287;
  int h = (int)(rem >> 13);            // 8192 = P_*N_
  float S = 0.f;
#pragma unroll
  for (int z = 0; z < NC_; ++z) {
    size_t off = (size_t)(b * 8 + z) * 524288 + rem;
    float old = st[off];
    st[off] = S;
    S = cdec[(b * 8 + z) * H_ + h] * S + old;
  }
}

// ---------------------------------------------------------------------------
// Y = Y_off + Y_diag + D*x per (b, chunk, head). bf16 out.
// ---------------------------------------------------------------------------
__global__ __launch_bounds__(256) void y_k(const ushort_t* __restrict__ xcb,
                                           const ushort_t* __restrict__ CB,
                                           const float* __restrict__ pv,
                                           const float* __restrict__ dacs,
                                           const float* __restrict__ dtp,
                                           const float* __restrict__ Dw,
                                           ushort_t* __restrict__ Y) {
  int bzh = blockIdx.x;
  int h = bzh & 63, z = (bzh >> 6) & 7, b = bzh >> 9;
  int g = h >> 3;
  int t = threadIdx.x;
  int rg = t & 63, pg = t >> 6, p0 = pg * 16;
  __shared__ float dAs[256], dts[256];
  __shared__ float prevT[32][68];          // [n_local][p]
  __shared__ float bigT[32 * 260];         // [col_local][i]
  __shared__ float xt[32][64];             // [j_local][p]
  {
    size_t base = ((size_t)b * H_ + h) * L_ + z * CS_;
    dAs[t] = dacs[base + t];
    dts[t] = dtp[base + t];
  }
  __syncthreads();
  float dAi[4];
#pragma unroll
  for (int ri = 0; ri < 4; ++ri) dAi[ri] = dAs[rg * 4 + ri];
  float acc[4][16];
#pragma unroll
  for (int ri = 0; ri < 4; ++ri)
#pragma unroll
    for (int pc = 0; pc < 16; ++pc) acc[ri][pc] = 0.f;

  size_t rowbase = (size_t)b * L_ + z * CS_;
  const float* pp0 = pv + ((size_t)((b * 8 + z) * H_ + h)) * (P_ * N_);

  // ---- Y_off: acc[i,p] = sum_n C[i,n] * prev[p,n], then scale by exp(dA_i)
  for (int nt = 0; nt < 4; ++nt) {
    __syncthreads();
#pragma unroll
    for (int u = 0; u < 4; ++u) {        // C tile transposed: 256 rows x 4 units
      int idx = t + u * 256;
      int i = idx >> 2, f = idx & 3;
      float v[8];
      ld_bf8(xcb + (rowbase + i) * CONVD_ + INTER_ + G_ * N_ + g * N_ + nt * 32 + f * 8, v);
#pragma unroll
      for (int c = 0; c < 8; ++c) bigT[(f * 8 + c) * 260 + i] = v[c];
    }
#pragma unroll
    for (int u = 0; u < 2; ++u) {        // prev tile transposed (fp32)
      int idx = t + u * 256;             // 512 f4 = 64 p x 8 f4
      int p = idx >> 3, f = idx & 7;
      float4 v = *(const float4*)(pp0 + (size_t)p * N_ + nt * 32 + f * 4);
      prevT[f*4+0][p] = v.x; prevT[f*4+1][p] = v.y;
      prevT[f*4+2][p] = v.z; prevT[f*4+3][p] = v.w;
    }
    __syncthreads();
    for (int nn = 0; nn < 32; ++nn) {
      float pvv[16];
#pragma unroll
      for (int q = 0; q < 4; ++q)
        *(float4*)&pvv[q * 4] = *(const float4*)&prevT[nn][p0 + q * 4];
      float4 cv = *(const float4*)&bigT[nn * 260 + rg * 4];
      float cvv[4] = {cv.x, cv.y, cv.z, cv.w};
#pragma unroll
      for (int ri = 0; ri < 4; ++ri)
#pragma unroll
        for (int pc = 0; pc < 16; ++pc)
          acc[ri][pc] = fmaf(cvv[ri], pvv[pc], acc[ri][pc]);
    }
  }
#pragma unroll
  for (int ri = 0; ri < 4; ++ri) {
    float e = __expf(dAi[ri]);
#pragma unroll
    for (int pc = 0; pc < 16; ++pc) acc[ri][pc] *= e;
  }

  // ---- Y_diag: acc[i,p] += sum_{j<=i} CB[i,j]*exp(dA_i-dA_j)*dt_j * x[j,p]
  size_t cbase = ((size_t)((b * 8 + z) * 8 + g)) * (CS_ * CS_);
  for (int j0 = 0; j0 < CS_; j0 += 32) {
    __syncthreads();
#pragma unroll
    for (int u = 0; u < 4; ++u) {        // CB tile transposed: 256 rows x 4 units
      int idx = t + u * 256;
      int i = idx >> 2, f = idx & 3;
      float v[8];
      ld_bf8(CB + cbase + (size_t)i * CS_ + j0 + f * 8, v);
#pragma unroll
      for (int c = 0; c < 8; ++c) bigT[(f * 8 + c) * 260 + i] = v[c];
    }
    {                                    // x tile: 32 rows x 8 units
      int jj = t >> 3, f = t & 7;
      float v[8];
      ld_bf8(xcb + (rowbase + j0 + jj) * CONVD_ + h * P_ + f * 8, v);
#pragma unroll
      for (int c = 0; c < 8; ++c) xt[jj][f * 8 + c] = v[c];
    }
    __syncthreads();
    int imax = rg * 4 + 3;
    for (int jj = 0; jj < 32; ++jj) {
      int j = j0 + jj;
      if (j > imax) break;
      float xv[16];
#pragma unroll
      for (int q = 0; q < 4; ++q)
        *(float4*)&xv[q * 4] = *(const float4*)&xt[jj][p0 + q * 4];
      float dAj = dAs[j], dtj = dts[j];
      float4 cb4 = *(const float4*)&bigT[jj * 260 + rg * 4];
      float cbv[4] = {cb4.x, cb4.y, cb4.z, cb4.w};
#pragma unroll
      for (int ri = 0; ri < 4; ++ri) {
        if (j <= rg * 4 + ri) {
          float m = cbv[ri] * __expf(dAi[ri] - dAj) * dtj;
#pragma unroll
          for (int pc = 0; pc < 16; ++pc) acc[ri][pc] = fmaf(m, xv[pc], acc[ri][pc]);
        }
      }
    }
  }

  // ---- + D*x, store bf16
  float Dh = Dw[h];
#pragma unroll
  for (int ri = 0; ri < 4; ++ri) {
    size_t row = rowbase + rg * 4 + ri;
    const ushort_t* xr = xcb + row * CONVD_ + h * P_ + p0;
    ushort_t* yr = Y + row * INTER_ + h * P_ + p0;
    float xv[16], o[16];
    ld_bf8(xr, xv);
    ld_bf8(xr + 8, xv + 8);
#pragma unroll
    for (int c = 0; c < 16; ++c) o[c] = acc[ri][c] + Dh * xv[c];
    st_bf8(yr, o);
    st_bf8(yr + 8, o + 8);
  }
}

// ---------------------------------------------------------------------------
// RMSNorm over INTER + silu(z) gate, in-place on bf16 Y. One block per row.
// ---------------------------------------------------------------------------
__global__ __launch_bounds__(256) void rms_gate_k(ushort_t* __restrict__ Y,
                                                  const ushort_t* __restrict__ zb,
                                                  const float* __restrict__ nw) {
  int row = blockIdx.x;
  int t = threadIdx.x;
  ushort_t* y = Y + (size_t)row * INTER_;
  const ushort_t* zp = zb + (size_t)row * PROJ_;
  float v[2][8];
  float s = 0.f;
#pragma unroll
  for (int u = 0; u < 2; ++u) {
    ld_bf8(y + u * 2048 + t * 8, v[u]);
#pragma unroll
    for (int c = 0; c < 8; ++c) s += v[u][c] * v[u][c];
  }
#pragma unroll
  for (int off = 32; off > 0; off >>= 1) s += __shfl_down(s, off);
  __shared__ float red[4];
  if ((t & 63) == 0) red[t >> 6] = s;
  __syncthreads();
  float tot = red[0] + red[1] + red[2] + red[3];
  float rstd = rsqrtf(tot * (1.f / INTER_) + EPS_);
#pragma unroll
  for (int u = 0; u < 2; ++u) {
    int c0 = u * 2048 + t * 8;
    float zv[8], o[8];
    ld_bf8(zp + c0, zv);
    float4 w0 = *(const float4*)(nw + c0);
    float4 w1 = *(const float4*)(nw + c0 + 4);
    float wv[8] = {w0.x, w0.y, w0.z, w0.w, w1.x, w1.y, w1.z, w1.w};
#pragma unroll
    for (int c = 0; c < 8; ++c)
      o[c] = wv[c] * v[u][c] * rstd * (zv[c] / (1.f + __expf(-zv[c])));
    st_bf8(y + c0, o);
  }
}

// ---------------------------------------------------------------------------
extern "C" void kernel_launch(void* const* d_in, const int* in_sizes, int n_in,
                              void* d_out, int out_size, void* d_ws, size_t ws_size,
                              hipStream_t stream) {
  const float* hs    = (const float*)d_in[0];
  const float* w_in  = (const float*)d_in[1];
  const float* cw    = (const float*)d_in[2];
  const float* cb    = (const float*)d_in[3];
  const float* dtb   = (const float*)d_in[4];
  const float* alog  = (const float*)d_in[5];
  const float* Dw    = (const float*)d_in[6];
  const float* nw    = (const float*)d_in[7];
  const float* w_out = (const float*)d_in[8];
  float* out = (float*)d_out;

  // Workspace layout (bytes): total ~211.5 MB
  ushort_t* zb    = (ushort_t*)d_ws;                       // 4096x10304 bf16 (84.4MB)
  ushort_t* xcb   = zb + (size_t)ML_ * PROJ_;              // 4096x6144  bf16 (50.3MB)
  float*    dtraw = (float*)(xcb + (size_t)ML_ * CONVD_);  // 4096x64    f32  (1MB)
  float*    dtp   = dtraw + 262144;                        // (B*H)xL    f32  (1MB)
  float*    dacs  = dtp + 262144;                          // (B*H)xL    f32  (1MB)
  float*    cdec  = dacs + 262144;                         // 1024       f32
  ushort_t* cbuf  = (ushort_t*)(cdec + 1024);              // 2*8*8*256*256 bf16 (16.8MB)
  float*    st    = (float*)(cbuf + (size_t)B_ * NC_ * G_ * CS_ * CS_); // 33.5MB (scan in place)
  ushort_t* Yb    = (ushort_t*)(st + (size_t)B_ * NC_ * H_ * P_ * N_);  // 4096x4096 bf16 (33.5MB)

  gemm1_k<<<dim3(81, 32), 256, 0, stream>>>(hs, w_in, zb, dtraw, ML_, PROJ_, HID_);
  conv_silu_k<<<(ML_ * (CONVD_ / 8)) / 256, 256, 0, stream>>>(zb, cw, cb, xcb);
  dt_scan_k<<<B_ * NC_ * H_, 256, 0, stream>>>(dtraw, dtb, alog, dtp, dacs, cdec);
  cb_k<<<dim3(16, B_ * NC_ * G_), 256, 0, stream>>>(xcb, cbuf);
  states_k<<<B_ * NC_ * H_, 256, 0, stream>>>(xcb, dacs, dtp, st);
  scan_k<<<(B_ * H_ * P_ * N_) / 256, 256, 0, stream>>>(st, cdec);
  y_k<<<B_ * NC_ * H_, 256, 0, stream>>>(xcb, cbuf, st, dacs, dtp, Dw, Yb);
  rms_gate_k<<<ML_, 256, 0, stream>>>(Yb, zb, nw);
  gemm2_k<<<dim3(16, 32), 256, 0, stream>>>(Yb, w_out, out, ML_, HID_, INTER_);
}

// Round 3
// 1116.418 us; speedup vs baseline: 3.3689x; 3.3689x over previous
//
#include <hip/hip_runtime.h>
#include <hip/hip_bf16.h>
#include <cstdint>
#include <cstddef>

#define H_     64
#define P_     64
#define G_     8
#define N_     128
#define K_     4
#define CS_    256
#define HID_   2048
#define INTER_ 4096
#define CONVD_ 6144
#define PROJ_  10304
#define ZSTR_  10240   /* zb row stride: z + xBC only (dt has fp32 sidecar) */
#define B_     2
#define L_     2048
#define NC_    8
#define ML_    4096    /* B_*L_ */
#define EPS_   1e-5f

typedef unsigned short ushort_t;
typedef __attribute__((ext_vector_type(8))) short short8;
typedef __attribute__((ext_vector_type(4))) float f32x4;

__device__ inline float b2f(ushort_t v) {
  unsigned u = ((unsigned)v) << 16;
  float f;
  __builtin_memcpy(&f, &u, 4);
  return f;
}
__device__ inline ushort_t f2b(float f) {
  unsigned u;
  __builtin_memcpy(&u, &f, 4);
  u = u + 0x7FFFu + ((u >> 16) & 1u);   // round-to-nearest-even
  return (ushort_t)(u >> 16);
}
__device__ inline void ld_bf8(const ushort_t* p, float* f) {
  uint4 u = *(const uint4*)p;
  const ushort_t* s = (const ushort_t*)&u;
#pragma unroll
  for (int c = 0; c < 8; ++c) f[c] = b2f(s[c]);
}
__device__ inline void st_bf8(ushort_t* p, const float* f) {
  uint4 u;
  ushort_t* s = (ushort_t*)&u;
#pragma unroll
  for (int c = 0; c < 8; ++c) s[c] = f2b(f[c]);
  *(uint4*)p = u;
}

// ---------------------------------------------------------------------------
// fp32 -> bf16 cast kernels
// ---------------------------------------------------------------------------
__global__ __launch_bounds__(256) void cast1_k(const float* __restrict__ hs,
                                               const float* __restrict__ w_in,
                                               ushort_t* __restrict__ hsb,
                                               ushort_t* __restrict__ w_inb) {
  size_t e8 = ((size_t)blockIdx.x * 256 + threadIdx.x) * 8;
  const float* src;
  ushort_t* dst;
  const size_t HSN = (size_t)ML_ * HID_;          // 8388608
  if (e8 < HSN) { src = hs + e8; dst = hsb + e8; }
  else          { src = w_in + (e8 - HSN); dst = w_inb + (e8 - HSN); }
  float4 a = *(const float4*)src;
  float4 b = *(const float4*)(src + 4);
  float v[8] = {a.x, a.y, a.z, a.w, b.x, b.y, b.z, b.w};
  st_bf8(dst, v);
}

__global__ __launch_bounds__(256) void cast2_k(const float* __restrict__ w_out,
                                               ushort_t* __restrict__ w_outb) {
  size_t e8 = ((size_t)blockIdx.x * 256 + threadIdx.x) * 8;
  float4 a = *(const float4*)(w_out + e8);
  float4 b = *(const float4*)(w_out + e8 + 4);
  float v[8] = {a.x, a.y, a.z, a.w, b.x, b.y, b.z, b.w};
  st_bf8(w_outb + e8, v);
}

// ---------------------------------------------------------------------------
// MFMA GEMM core: 128x128 tile, BK=32, 256 thr = 4 waves (2x2 of 64x64),
// each wave 4x4 frags of 16x16x32 bf16 MFMA. NT layout (both row-major in K).
// global_load_lds width-16 staging; LDS tiles row-major [128][32] bf16.
// ---------------------------------------------------------------------------
typedef const __attribute__((address_space(1))) unsigned int gu32;
typedef __attribute__((address_space(3))) unsigned int lu32;
__device__ __forceinline__ void gl_lds16(const ushort_t* g, ushort_t* l) {
  __builtin_amdgcn_global_load_lds((gu32*)g, (lu32*)l, 16, 0, 0);
}

__device__ __forceinline__ void mfma_tile(const ushort_t* __restrict__ A,
                                          const ushort_t* __restrict__ B,
                                          int lda, int ldb, int Kd,
                                          int bm, int bn, int brmax,
                                          ushort_t* As, ushort_t* Bs,
                                          f32x4 acc[4][4]) {
  int t = threadIdx.x;
  int wave = t >> 6, lane = t & 63;
  int mr = (wave >> 1) * 64, nr = (wave & 1) * 64;
  int ml = lane & 15, ko = (lane >> 4) * 8;
  for (int k0 = 0; k0 < Kd; k0 += 32) {
#pragma unroll
    for (int u = 0; u < 2; ++u) {
      int s = wave * 128 + u * 64 + lane;      // segment id: row = s>>2, kc = (s&3)*8
      int row = s >> 2, kc = (s & 3) * 8;
      // LDS dest is wave-uniform base + lane*16
      gl_lds16(A + (size_t)(bm + row) * lda + k0 + kc,
               As + (size_t)(wave * 128 + u * 64) * 8);
      int brow = bn + row; if (brow > brmax) brow = brmax;
      gl_lds16(B + (size_t)brow * ldb + k0 + kc,
               Bs + (size_t)(wave * 128 + u * 64) * 8);
    }
    __syncthreads();
    short8 af[4], bf[4];
#pragma unroll
    for (int i = 0; i < 4; ++i)
      af[i] = *(const short8*)(As + (mr + i * 16 + ml) * 32 + ko);
#pragma unroll
    for (int j = 0; j < 4; ++j)
      bf[j] = *(const short8*)(Bs + (nr + j * 16 + ml) * 32 + ko);
#pragma unroll
    for (int i = 0; i < 4; ++i)
#pragma unroll
      for (int j = 0; j < 4; ++j)
        acc[i][j] = __builtin_amdgcn_mfma_f32_16x16x32_bf16(af[i], bf[j], acc[i][j], 0, 0, 0);
    __syncthreads();
  }
}

// GEMM1: zxbcdt = hs @ in_proj_w^T. Tiles 0..79 -> bf16 zb (stride ZSTR_);
// tile 80 cols 10240..10303 -> fp32 dtraw sidecar (full precision dt path).
__global__ __launch_bounds__(256) void gemm1_mfma(const ushort_t* __restrict__ hsb,
                                                  const ushort_t* __restrict__ w_inb,
                                                  ushort_t* __restrict__ zb,
                                                  float* __restrict__ dtraw) {
  __shared__ __align__(16) ushort_t As[128 * 32];
  __shared__ __align__(16) ushort_t Bs[128 * 32];
  f32x4 acc[4][4];
#pragma unroll
  for (int i = 0; i < 4; ++i)
#pragma unroll
    for (int j = 0; j < 4; ++j) acc[i][j] = (f32x4){0.f, 0.f, 0.f, 0.f};
  int bm = blockIdx.y * 128, bn = blockIdx.x * 128;
  mfma_tile(hsb, w_inb, HID_, HID_, HID_, bm, bn, PROJ_ - 1, As, Bs, acc);
  int t = threadIdx.x, wave = t >> 6, lane = t & 63;
  int mr = (wave >> 1) * 64, nr = (wave & 1) * 64;
  int colb = bn + nr + (lane & 15);
  int rowb = bm + mr + (lane >> 4) * 4;
  if (blockIdx.x < 80) {
#pragma unroll
    for (int i = 0; i < 4; ++i)
#pragma unroll
      for (int r = 0; r < 4; ++r) {
        int row = rowb + i * 16 + r;
#pragma unroll
        for (int j = 0; j < 4; ++j)
          zb[(size_t)row * ZSTR_ + colb + j * 16] = f2b(acc[i][j][r]);
      }
  } else if (nr == 0) {   // dt columns 10240..10303, fp32 sidecar
#pragma unroll
    for (int i = 0; i < 4; ++i)
#pragma unroll
      for (int r = 0; r < 4; ++r) {
        int row = rowb + i * 16 + r;
#pragma unroll
        for (int j = 0; j < 4; ++j)
          dtraw[(size_t)row * 64 + (colb - ZSTR_) + j * 16] = acc[i][j][r];
      }
  }
}

// GEMM2: out = Y @ out_proj_w^T. A = normalized Y in xcb x-slice (stride CONVD_).
__global__ __launch_bounds__(256) void gemm2_mfma(const ushort_t* __restrict__ Ab,
                                                  const ushort_t* __restrict__ Bb,
                                                  float* __restrict__ C) {
  __shared__ __align__(16) ushort_t As[128 * 32];
  __shared__ __align__(16) ushort_t Bs[128 * 32];
  f32x4 acc[4][4];
#pragma unroll
  for (int i = 0; i < 4; ++i)
#pragma unroll
    for (int j = 0; j < 4; ++j) acc[i][j] = (f32x4){0.f, 0.f, 0.f, 0.f};
  int bm = blockIdx.y * 128, bn = blockIdx.x * 128;
  mfma_tile(Ab, Bb, CONVD_, INTER_, INTER_, bm, bn, HID_ - 1, As, Bs, acc);
  int t = threadIdx.x, wave = t >> 6, lane = t & 63;
  int mr = (wave >> 1) * 64, nr = (wave & 1) * 64;
  int colb = bn + nr + (lane & 15);
  int rowb = bm + mr + (lane >> 4) * 4;
#pragma unroll
  for (int i = 0; i < 4; ++i)
#pragma unroll
    for (int r = 0; r < 4; ++r) {
      int row = rowb + i * 16 + r;
#pragma unroll
      for (int j = 0; j < 4; ++j)
        C[(size_t)row * HID_ + colb + j * 16] = acc[i][j][r];
    }
}

// ---------------------------------------------------------------------------
// Causal depthwise conv (K=4) + SiLU, bf16 in (zb xBC slice) -> bf16 out.
// ---------------------------------------------------------------------------
__global__ __launch_bounds__(256) void conv_silu_k(const ushort_t* __restrict__ zb,
                                                   const float* __restrict__ cw,
                                                   const float* __restrict__ cb,
                                                   ushort_t* __restrict__ xcb) {
  int idx = blockIdx.x * 256 + threadIdx.x;     // ML_ * 768 units
  int c8 = (idx % 768) * 8;
  int row = idx / 768;
  int l = row % L_;
  float a[8];
#pragma unroll
  for (int c = 0; c < 8; ++c) a[c] = cb[c8 + c];
#pragma unroll
  for (int i = 0; i < K_; ++i) {
    int ll = l - (K_ - 1) + i;
    if (ll >= 0) {
      float xv[8];
      ld_bf8(zb + (size_t)(row - (K_ - 1) + i) * ZSTR_ + INTER_ + c8, xv);
#pragma unroll
      for (int c = 0; c < 8; ++c) a[c] = fmaf(cw[(c8 + c) * K_ + i], xv[c], a[c]);
    }
  }
#pragma unroll
  for (int c = 0; c < 8; ++c) a[c] = a[c] / (1.f + __expf(-a[c]));
  st_bf8(xcb + (size_t)row * CONVD_ + c8, a);
}

// ---------------------------------------------------------------------------
// dt: softplus(dtraw + bias); dA = dt*A; inclusive cumsum per chunk (CS=256).
// ---------------------------------------------------------------------------
__global__ __launch_bounds__(256) void dt_scan_k(const float* __restrict__ dtraw,
                                                 const float* __restrict__ dt_bias,
                                                 const float* __restrict__ A_log,
                                                 float* __restrict__ dtp,
                                                 float* __restrict__ dacs,
                                                 float* __restrict__ cdec) {
  int bzh = blockIdx.x;
  int h = bzh & 63, z = (bzh >> 6) & 7, b = bzh >> 9;
  int i = threadIdx.x;
  size_t row = (size_t)b * L_ + z * CS_ + i;
  float dv = dtraw[row * 64 + h] + dt_bias[h];
  float sp = (dv > 20.f) ? dv : log1pf(expf(dv));
  float v = sp * (-expf(A_log[h]));
  __shared__ float sm[256];
  sm[i] = v;
  __syncthreads();
  for (int off = 1; off < 256; off <<= 1) {
    float add = (i >= off) ? sm[i - off] : 0.f;
    __syncthreads();
    sm[i] += add;
    __syncthreads();
  }
  float cs = sm[i];
  size_t ob = ((size_t)b * H_ + h) * L_ + z * CS_ + i;
  dtp[ob] = sp;
  dacs[ob] = cs;
  if (i == CS_ - 1) cdec[bzh] = expf(cs);
}

// ---------------------------------------------------------------------------
// CB[i,j] = sum_n C[i,n]*B[j,n], lower-triangular 64x64 tiles only. bf16 out.
// ---------------------------------------------------------------------------
__global__ __launch_bounds__(256) void cb_k(const ushort_t* __restrict__ xcb,
                                            ushort_t* __restrict__ CBo) {
  int jt = blockIdx.x & 3, it = blockIdx.x >> 2;
  if (jt > it) return;
  int bzg = blockIdx.y;
  int g = bzg & 7, z = (bzg >> 3) & 7, b = bzg >> 6;
  int t = threadIdx.x;
  int tx = t & 15, ty = t >> 4;
  __shared__ float CtT[64][68];   // [n_local][i_local]
  __shared__ float BtT[64][68];   // [n_local][j_local]
  size_t rowbase = (size_t)b * L_ + (size_t)z * CS_;
  float acc[4][4];
#pragma unroll
  for (int i = 0; i < 4; ++i)
#pragma unroll
    for (int j = 0; j < 4; ++j) acc[i][j] = 0.f;

  for (int half = 0; half < 2; ++half) {
    int nb = half * 64;
    __syncthreads();
#pragma unroll
    for (int u = 0; u < 2; ++u) {
      int idx = t + u * 256;            // 512 units of 8 bf16 = 64 rows x 8
      int rr = idx >> 3, f = idx & 7;
      float cv[8], bv[8];
      ld_bf8(xcb + (rowbase + it * 64 + rr) * CONVD_ + INTER_ + G_ * N_ + g * N_ + nb + f * 8, cv);
      ld_bf8(xcb + (rowbase + jt * 64 + rr) * CONVD_ + INTER_ + g * N_ + nb + f * 8, bv);
#pragma unroll
      for (int c = 0; c < 8; ++c) { CtT[f * 8 + c][rr] = cv[c]; BtT[f * 8 + c][rr] = bv[c]; }
    }
    __syncthreads();
    for (int n = 0; n < 64; ++n) {
      float4 cv = *(const float4*)&CtT[n][ty * 4];
      float4 bv = *(const float4*)&BtT[n][tx * 4];
      float cc[4] = {cv.x, cv.y, cv.z, cv.w};
      float bb[4] = {bv.x, bv.y, bv.z, bv.w};
#pragma unroll
      for (int i = 0; i < 4; ++i)
#pragma unroll
        for (int j = 0; j < 4; ++j) acc[i][j] = fmaf(cc[i], bb[j], acc[i][j]);
    }
  }
  size_t cbase = ((size_t)((b * 8 + z) * 8 + g)) * (CS_ * CS_);
#pragma unroll
  for (int i = 0; i < 4; ++i) {
    int row = it * 64 + ty * 4 + i;
    ushort4 v;
    v.x = f2b(acc[i][0]); v.y = f2b(acc[i][1]); v.z = f2b(acc[i][2]); v.w = f2b(acc[i][3]);
    *(ushort4*)(CBo + cbase + (size_t)row * CS_ + jt * 64 + tx * 4) = v;
  }
}

// ---------------------------------------------------------------------------
// Per-chunk states: S[p,n] = sum_j x[j,p]*w[j]*B[j,n]. fp32 out.
// ---------------------------------------------------------------------------
__global__ __launch_bounds__(256) void states_k(const ushort_t* __restrict__ xcb,
                                                const float* __restrict__ dacs,
                                                const float* __restrict__ dtp,
                                                float* __restrict__ st) {
  int bzh = blockIdx.x;
  int h = bzh & 63, z = (bzh >> 6) & 7, b = bzh >> 9;
  int g = h >> 3;
  int t = threadIdx.x;
  __shared__ float ws[256];
  __shared__ float xt[64][64];
  __shared__ float Bt[64][128];
  size_t base = ((size_t)b * H_ + h) * L_ + z * CS_;
  float dlast = dacs[base + CS_ - 1];
  ws[t] = __expf(dlast - dacs[base + t]) * dtp[base + t];
  int p0 = (t & 15) * 4, n0 = (t >> 4) * 8;
  float acc[4][8];
#pragma unroll
  for (int i = 0; i < 4; ++i)
#pragma unroll
    for (int j = 0; j < 8; ++j) acc[i][j] = 0.f;
  size_t rowbase = (size_t)b * L_ + z * CS_;

  for (int j0 = 0; j0 < CS_; j0 += 64) {
    __syncthreads();
#pragma unroll
    for (int u = 0; u < 2; ++u) {       // x: 64 rows x 8 units
      int idx = t + u * 256;
      int rr = idx >> 3, f = idx & 7;
      float xv[8];
      ld_bf8(xcb + (rowbase + j0 + rr) * CONVD_ + h * P_ + f * 8, xv);
#pragma unroll
      for (int c = 0; c < 8; ++c) xt[rr][f * 8 + c] = xv[c];
    }
#pragma unroll
    for (int u = 0; u < 4; ++u) {       // B: 64 rows x 16 units
      int idx = t + u * 256;
      int rr = idx >> 4, f = idx & 15;
      float bv[8];
      ld_bf8(xcb + (rowbase + j0 + rr) * CONVD_ + INTER_ + g * N_ + f * 8, bv);
#pragma unroll
      for (int c = 0; c < 8; ++c) Bt[rr][f * 8 + c] = bv[c];
    }
    __syncthreads();
    for (int jj = 0; jj < 64; ++jj) {
      float wj = ws[j0 + jj];
      float4 xv = *(const float4*)&xt[jj][p0];
      float xw[4] = {xv.x * wj, xv.y * wj, xv.z * wj, xv.w * wj};
      float4 b0v = *(const float4*)&Bt[jj][n0];
      float4 b1v = *(const float4*)&Bt[jj][n0 + 4];
      float bb[8] = {b0v.x, b0v.y, b0v.z, b0v.w, b1v.x, b1v.y, b1v.z, b1v.w};
#pragma unroll
      for (int pp = 0; pp < 4; ++pp)
#pragma unroll
        for (int nn = 0; nn < 8; ++nn) acc[pp][nn] = fmaf(xw[pp], bb[nn], acc[pp][nn]);
    }
  }
  float* outp = st + ((size_t)((b * 8 + z) * H_ + h)) * (P_ * N_);
#pragma unroll
  for (int pp = 0; pp < 4; ++pp) {
    *(float4*)(outp + (size_t)(p0 + pp) * N_ + n0) =
        make_float4(acc[pp][0], acc[pp][1], acc[pp][2], acc[pp][3]);
    *(float4*)(outp + (size_t)(p0 + pp) * N_ + n0 + 4) =
        make_float4(acc[pp][4], acc[pp][5], acc[pp][6], acc[pp][7]);
  }
}

// ---------------------------------------------------------------------------
// Inter-chunk exclusive scan over nc=8 chunks, IN PLACE on st.
// ---------------------------------------------------------------------------
__global__ __launch_bounds__(256) void scan_k(float* __restrict__ st,
                                              const float* __restrict__ cdec) {
  size_t idx = (size_t)blockIdx.x * 256 + threadIdx.x;
  int b = (int)(idx >> 19);            // 524288 = H_*P_*N_
  size_t rem = idx & 524287;
  int h = (int)(rem >> 13);            // 8192 = P_*N_
  float S = 0.f;
#pragma unroll
  for (int z = 0; z < NC_; ++z) {
    size_t off = (size_t)(b * 8 + z) * 524288 + rem;
    float old = st[off];
    st[off] = S;
    S = cdec[(b * 8 + z) * H_ + h] * S + old;
  }
}

// ---------------------------------------------------------------------------
// Y = Y_off + Y_diag + D*x per (b, chunk, head). Writes Y IN PLACE over the
// x-slice of xcb (block-local read/write region; all global x reads precede
// the epilogue's own read-then-write).
// ---------------------------------------------------------------------------
__global__ __launch_bounds__(256) void y_k(const ushort_t* xcb,
                                           const ushort_t* __restrict__ CB,
                                           const float* __restrict__ pv,
                                           const float* __restrict__ dacs,
                                           const float* __restrict__ dtp,
                                           const float* __restrict__ Dw,
                                           ushort_t* Yx) {
  int bzh = blockIdx.x;
  int h = bzh & 63, z = (bzh >> 6) & 7, b = bzh >> 9;
  int g = h >> 3;
  int t = threadIdx.x;
  int rg = t & 63, pg = t >> 6, p0 = pg * 16;
  __shared__ float dAs[256], dts[256];
  __shared__ float prevT[32][68];          // [n_local][p]
  __shared__ float bigT[32 * 260];         // [col_local][i]
  __shared__ float xt[32][64];             // [j_local][p]
  {
    size_t base = ((size_t)b * H_ + h) * L_ + z * CS_;
    dAs[t] = dacs[base + t];
    dts[t] = dtp[base + t];
  }
  __syncthreads();
  float dAi[4];
#pragma unroll
  for (int ri = 0; ri < 4; ++ri) dAi[ri] = dAs[rg * 4 + ri];
  float acc[4][16];
#pragma unroll
  for (int ri = 0; ri < 4; ++ri)
#pragma unroll
    for (int pc = 0; pc < 16; ++pc) acc[ri][pc] = 0.f;

  size_t rowbase = (size_t)b * L_ + z * CS_;
  const float* pp0 = pv + ((size_t)((b * 8 + z) * H_ + h)) * (P_ * N_);

  // ---- Y_off
  for (int nt = 0; nt < 4; ++nt) {
    __syncthreads();
#pragma unroll
    for (int u = 0; u < 4; ++u) {
      int idx = t + u * 256;
      int i = idx >> 2, f = idx & 3;
      float v[8];
      ld_bf8(xcb + (rowbase + i) * CONVD_ + INTER_ + G_ * N_ + g * N_ + nt * 32 + f * 8, v);
#pragma unroll
      for (int c = 0; c < 8; ++c) bigT[(f * 8 + c) * 260 + i] = v[c];
    }
#pragma unroll
    for (int u = 0; u < 2; ++u) {
      int idx = t + u * 256;
      int p = idx >> 3, f = idx & 7;
      float4 v = *(const float4*)(pp0 + (size_t)p * N_ + nt * 32 + f * 4);
      prevT[f*4+0][p] = v.x; prevT[f*4+1][p] = v.y;
      prevT[f*4+2][p] = v.z; prevT[f*4+3][p] = v.w;
    }
    __syncthreads();
    for (int nn = 0; nn < 32; ++nn) {
      float pvv[16];
#pragma unroll
      for (int q = 0; q < 4; ++q)
        *(float4*)&pvv[q * 4] = *(const float4*)&prevT[nn][p0 + q * 4];
      float4 cv = *(const float4*)&bigT[nn * 260 + rg * 4];
      float cvv[4] = {cv.x, cv.y, cv.z, cv.w};
#pragma unroll
      for (int ri = 0; ri < 4; ++ri)
#pragma unroll
        for (int pc = 0; pc < 16; ++pc)
          acc[ri][pc] = fmaf(cvv[ri], pvv[pc], acc[ri][pc]);
    }
  }
#pragma unroll
  for (int ri = 0; ri < 4; ++ri) {
    float e = __expf(dAi[ri]);
#pragma unroll
    for (int pc = 0; pc < 16; ++pc) acc[ri][pc] *= e;
  }

  // ---- Y_diag
  size_t cbase = ((size_t)((b * 8 + z) * 8 + g)) * (CS_ * CS_);
  for (int j0 = 0; j0 < CS_; j0 += 32) {
    __syncthreads();
#pragma unroll
    for (int u = 0; u < 4; ++u) {
      int idx = t + u * 256;
      int i = idx >> 2, f = idx & 3;
      float v[8];
      ld_bf8(CB + cbase + (size_t)i * CS_ + j0 + f * 8, v);
#pragma unroll
      for (int c = 0; c < 8; ++c) bigT[(f * 8 + c) * 260 + i] = v[c];
    }
    {
      int jj = t >> 3, f = t & 7;
      float v[8];
      ld_bf8(xcb + (rowbase + j0 + jj) * CONVD_ + h * P_ + f * 8, v);
#pragma unroll
      for (int c = 0; c < 8; ++c) xt[jj][f * 8 + c] = v[c];
    }
    __syncthreads();
    int imax = rg * 4 + 3;
    for (int jj = 0; jj < 32; ++jj) {
      int j = j0 + jj;
      if (j > imax) break;
      float xv[16];
#pragma unroll
      for (int q = 0; q < 4; ++q)
        *(float4*)&xv[q * 4] = *(const float4*)&xt[jj][p0 + q * 4];
      float dAj = dAs[j], dtj = dts[j];
      float4 cb4 = *(const float4*)&bigT[jj * 260 + rg * 4];
      float cbv[4] = {cb4.x, cb4.y, cb4.z, cb4.w};
#pragma unroll
      for (int ri = 0; ri < 4; ++ri) {
        if (j <= rg * 4 + ri) {
          float m = cbv[ri] * __expf(dAi[ri] - dAj) * dtj;
#pragma unroll
          for (int pc = 0; pc < 16; ++pc) acc[ri][pc] = fmaf(m, xv[pc], acc[ri][pc]);
        }
      }
    }
  }

  // ---- + D*x, store bf16 in place over x-slice
  float Dh = Dw[h];
#pragma unroll
  for (int ri = 0; ri < 4; ++ri) {
    size_t row = rowbase + rg * 4 + ri;
    const ushort_t* xr = xcb + row * CONVD_ + h * P_ + p0;
    ushort_t* yr = Yx + row * CONVD_ + h * P_ + p0;
    float xv[16], o[16];
    ld_bf8(xr, xv);
    ld_bf8(xr + 8, xv + 8);
#pragma unroll
    for (int c = 0; c < 16; ++c) o[c] = acc[ri][c] + Dh * xv[c];
    st_bf8(yr, o);
    st_bf8(yr + 8, o + 8);
  }
}

// ---------------------------------------------------------------------------
// RMSNorm + silu(z) gate, in-place on xcb x-slice (stride CONVD_).
// ---------------------------------------------------------------------------
__global__ __launch_bounds__(256) void rms_gate_k(ushort_t* __restrict__ Y,
                                                  const ushort_t* __restrict__ zb,
                                                  const float* __restrict__ nw) {
  int row = blockIdx.x;
  int t = threadIdx.x;
  ushort_t* y = Y + (size_t)row * CONVD_;
  const ushort_t* zp = zb + (size_t)row * ZSTR_;
  float v[2][8];
  float s = 0.f;
#pragma unroll
  for (int u = 0; u < 2; ++u) {
    ld_bf8(y + u * 2048 + t * 8, v[u]);
#pragma unroll
    for (int c = 0; c < 8; ++c) s += v[u][c] * v[u][c];
  }
#pragma unroll
  for (int off = 32; off > 0; off >>= 1) s += __shfl_down(s, off);
  __shared__ float red[4];
  if ((t & 63) == 0) red[t >> 6] = s;
  __syncthreads();
  float tot = red[0] + red[1] + red[2] + red[3];
  float rstd = rsqrtf(tot * (1.f / INTER_) + EPS_);
#pragma unroll
  for (int u = 0; u < 2; ++u) {
    int c0 = u * 2048 + t * 8;
    float zv[8], o[8];
    ld_bf8(zp + c0, zv);
    float4 w0 = *(const float4*)(nw + c0);
    float4 w1 = *(const float4*)(nw + c0 + 4);
    float wv[8] = {w0.x, w0.y, w0.z, w0.w, w1.x, w1.y, w1.z, w1.w};
#pragma unroll
    for (int c = 0; c < 8; ++c)
      o[c] = wv[c] * v[u][c] * rstd * (zv[c] / (1.f + __expf(-zv[c])));
    st_bf8(y + c0, o);
  }
}

// ---------------------------------------------------------------------------
extern "C" void kernel_launch(void* const* d_in, const int* in_sizes, int n_in,
                              void* d_out, int out_size, void* d_ws, size_t ws_size,
                              hipStream_t stream) {
  const float* hs    = (const float*)d_in[0];
  const float* w_in  = (const float*)d_in[1];
  const float* cw    = (const float*)d_in[2];
  const float* cb    = (const float*)d_in[3];
  const float* dtb   = (const float*)d_in[4];
  const float* alog  = (const float*)d_in[5];
  const float* Dw    = (const float*)d_in[6];
  const float* nw    = (const float*)d_in[7];
  const float* w_out = (const float*)d_in[8];
  float* out = (float*)d_out;

  // Workspace layout (~187.3 MiB), regions R1/R2 time-aliased:
  //   R1 (16.78 MB): hsb [cast1,gemm1] -> cbuf [cb_k..y_k] -> w_outb [cast2,gemm2]
  //   R2 (42.20 MB): w_inb [cast1,gemm1] -> st [states..y_k]
  char* base = (char*)d_ws;
  ushort_t* zb    = (ushort_t*)(base);                         //  83,886,080 B
  ushort_t* xcb   = (ushort_t*)(base + 83886080);              //  50,331,648 B
  float*    dtraw = (float*)(base + 134217728);                //   1,048,576 B
  float*    dtp   = (float*)(base + 135266304);                //   1,048,576 B
  float*    dacs  = (float*)(base + 136314880);                //   1,048,576 B
  float*    cdec  = (float*)(base + 137363456);                //       4,096 B
  char*     R1    = base + 137367552;                          //  16,777,216 B
  char*     R2    = base + 154144768;                          //  42,205,184 B (end 196,349,952)
  ushort_t* hsb    = (ushort_t*)R1;
  ushort_t* cbuf   = (ushort_t*)R1;
  ushort_t* w_outb = (ushort_t*)R1;
  ushort_t* w_inb  = (ushort_t*)R2;
  float*    st     = (float*)R2;

  cast1_k<<<14400, 256, 0, stream>>>(hs, w_in, hsb, w_inb);
  gemm1_mfma<<<dim3(81, 32), 256, 0, stream>>>(hsb, w_inb, zb, dtraw);
  conv_silu_k<<<(ML_ * (CONVD_ / 8)) / 256, 256, 0, stream>>>(zb, cw, cb, xcb);
  dt_scan_k<<<B_ * NC_ * H_, 256, 0, stream>>>(dtraw, dtb, alog, dtp, dacs, cdec);
  cb_k<<<dim3(16, B_ * NC_ * G_), 256, 0, stream>>>(xcb, cbuf);
  states_k<<<B_ * NC_ * H_, 256, 0, stream>>>(xcb, dacs, dtp, st);
  scan_k<<<(B_ * H_ * P_ * N_) / 256, 256, 0, stream>>>(st, cdec);
  y_k<<<B_ * NC_ * H_, 256, 0, stream>>>(xcb, cbuf, st, dacs, dtp, Dw, xcb);
  rms_gate_k<<<ML_, 256, 0, stream>>>(xcb, zb, nw);
  cast2_k<<<4096, 256, 0, stream>>>(w_out, w_outb);
  gemm2_mfma<<<dim3(16, 32), 256, 0, stream>>>(xcb, w_outb, out);
}

// Round 4
// 900.970 us; speedup vs baseline: 4.1745x; 1.2391x over previous
//
#include <hip/hip_runtime.h>
#include <hip/hip_bf16.h>
#include <cstdint>
#include <cstddef>

#define H_     64
#define P_     64
#define G_     8
#define N_     128
#define K_     4
#define CS_    256
#define HID_   2048
#define INTER_ 4096
#define CONVD_ 6144
#define PROJ_  10304
#define ZSTR_  10240   /* zb row stride: z + xBC only (dt has fp32 sidecar) */
#define B_     2
#define L_     2048
#define NC_    8
#define ML_    4096    /* B_*L_ */
#define EPS_   1e-5f

typedef unsigned short ushort_t;
typedef __attribute__((ext_vector_type(8))) short short8;
typedef __attribute__((ext_vector_type(4))) float f32x4;

__device__ inline float b2f(ushort_t v) {
  unsigned u = ((unsigned)v) << 16;
  float f;
  __builtin_memcpy(&f, &u, 4);
  return f;
}
__device__ inline ushort_t f2b(float f) {
  unsigned u;
  __builtin_memcpy(&u, &f, 4);
  u = u + 0x7FFFu + ((u >> 16) & 1u);   // round-to-nearest-even
  return (ushort_t)(u >> 16);
}
__device__ inline void ld_bf8(const ushort_t* p, float* f) {
  uint4 u = *(const uint4*)p;
  const ushort_t* s = (const ushort_t*)&u;
#pragma unroll
  for (int c = 0; c < 8; ++c) f[c] = b2f(s[c]);
}
__device__ inline void st_bf8(ushort_t* p, const float* f) {
  uint4 u;
  ushort_t* s = (ushort_t*)&u;
#pragma unroll
  for (int c = 0; c < 8; ++c) s[c] = f2b(f[c]);
  *(uint4*)p = u;
}

// ---------------------------------------------------------------------------
// fp32 -> bf16 cast kernels
// ---------------------------------------------------------------------------
__global__ __launch_bounds__(256) void cast1_k(const float* __restrict__ hs,
                                               const float* __restrict__ w_in,
                                               ushort_t* __restrict__ hsb,
                                               ushort_t* __restrict__ w_inb) {
  size_t e8 = ((size_t)blockIdx.x * 256 + threadIdx.x) * 8;
  const float* src;
  ushort_t* dst;
  const size_t HSN = (size_t)ML_ * HID_;          // 8388608
  if (e8 < HSN) { src = hs + e8; dst = hsb + e8; }
  else          { src = w_in + (e8 - HSN); dst = w_inb + (e8 - HSN); }
  float4 a = *(const float4*)src;
  float4 b = *(const float4*)(src + 4);
  float v[8] = {a.x, a.y, a.z, a.w, b.x, b.y, b.z, b.w};
  st_bf8(dst, v);
}

__global__ __launch_bounds__(256) void cast2_k(const float* __restrict__ w_out,
                                               ushort_t* __restrict__ w_outb) {
  size_t e8 = ((size_t)blockIdx.x * 256 + threadIdx.x) * 8;
  float4 a = *(const float4*)(w_out + e8);
  float4 b = *(const float4*)(w_out + e8 + 4);
  float v[8] = {a.x, a.y, a.z, a.w, b.x, b.y, b.z, b.w};
  st_bf8(w_outb + e8, v);
}

// ---------------------------------------------------------------------------
// MFMA GEMM core: 128x128 tile, BK=32, 256 thr = 4 waves (2x2 of 64x64),
// each wave 4x4 frags of 16x16x32 bf16 MFMA.
// ---------------------------------------------------------------------------
typedef const __attribute__((address_space(1))) unsigned int gu32;
typedef __attribute__((address_space(3))) unsigned int lu32;
__device__ __forceinline__ void gl_lds16(const ushort_t* g, ushort_t* l) {
  __builtin_amdgcn_global_load_lds((gu32*)g, (lu32*)l, 16, 0, 0);
}

__device__ __forceinline__ void mfma_tile(const ushort_t* __restrict__ A,
                                          const ushort_t* __restrict__ B,
                                          int lda, int ldb, int Kd,
                                          int bm, int bn, int brmax,
                                          ushort_t* As, ushort_t* Bs,
                                          f32x4 acc[4][4]) {
  int t = threadIdx.x;
  int wave = t >> 6, lane = t & 63;
  int mr = (wave >> 1) * 64, nr = (wave & 1) * 64;
  int ml = lane & 15, ko = (lane >> 4) * 8;
  for (int k0 = 0; k0 < Kd; k0 += 32) {
#pragma unroll
    for (int u = 0; u < 2; ++u) {
      int s = wave * 128 + u * 64 + lane;      // row = s>>2, kc = (s&3)*8
      int row = s >> 2, kc = (s & 3) * 8;
      gl_lds16(A + (size_t)(bm + row) * lda + k0 + kc,
               As + (size_t)(wave * 128 + u * 64) * 8);
      int brow = bn + row; if (brow > brmax) brow = brmax;
      gl_lds16(B + (size_t)brow * ldb + k0 + kc,
               Bs + (size_t)(wave * 128 + u * 64) * 8);
    }
    __syncthreads();
    short8 af[4], bf[4];
#pragma unroll
    for (int i = 0; i < 4; ++i)
      af[i] = *(const short8*)(As + (mr + i * 16 + ml) * 32 + ko);
#pragma unroll
    for (int j = 0; j < 4; ++j)
      bf[j] = *(const short8*)(Bs + (nr + j * 16 + ml) * 32 + ko);
#pragma unroll
    for (int i = 0; i < 4; ++i)
#pragma unroll
      for (int j = 0; j < 4; ++j)
        acc[i][j] = __builtin_amdgcn_mfma_f32_16x16x32_bf16(af[i], bf[j], acc[i][j], 0, 0, 0);
    __syncthreads();
  }
}

// GEMM1: grid (32 row-tiles fastest, 81 col-tiles) for B-panel L2 locality.
__global__ __launch_bounds__(256) void gemm1_mfma(const ushort_t* __restrict__ hsb,
                                                  const ushort_t* __restrict__ w_inb,
                                                  ushort_t* __restrict__ zb,
                                                  float* __restrict__ dtraw) {
  __shared__ __align__(16) ushort_t As[128 * 32];
  __shared__ __align__(16) ushort_t Bs[128 * 32];
  f32x4 acc[4][4];
#pragma unroll
  for (int i = 0; i < 4; ++i)
#pragma unroll
    for (int j = 0; j < 4; ++j) acc[i][j] = (f32x4){0.f, 0.f, 0.f, 0.f};
  int bm = blockIdx.x * 128, bn = blockIdx.y * 128;
  mfma_tile(hsb, w_inb, HID_, HID_, HID_, bm, bn, PROJ_ - 1, As, Bs, acc);
  int t = threadIdx.x, wave = t >> 6, lane = t & 63;
  int mr = (wave >> 1) * 64, nr = (wave & 1) * 64;
  int colb = bn + nr + (lane & 15);
  int rowb = bm + mr + (lane >> 4) * 4;
  if (blockIdx.y < 80) {
#pragma unroll
    for (int i = 0; i < 4; ++i)
#pragma unroll
      for (int r = 0; r < 4; ++r) {
        int row = rowb + i * 16 + r;
#pragma unroll
        for (int j = 0; j < 4; ++j)
          zb[(size_t)row * ZSTR_ + colb + j * 16] = f2b(acc[i][j][r]);
      }
  } else if (nr == 0) {   // dt columns 10240..10303, fp32 sidecar
#pragma unroll
    for (int i = 0; i < 4; ++i)
#pragma unroll
      for (int r = 0; r < 4; ++r) {
        int row = rowb + i * 16 + r;
#pragma unroll
        for (int j = 0; j < 4; ++j)
          dtraw[(size_t)row * 64 + (colb - ZSTR_) + j * 16] = acc[i][j][r];
      }
  }
}

// GEMM2: out = Y @ out_proj_w^T.
__global__ __launch_bounds__(256) void gemm2_mfma(const ushort_t* __restrict__ Ab,
                                                  const ushort_t* __restrict__ Bb,
                                                  float* __restrict__ C) {
  __shared__ __align__(16) ushort_t As[128 * 32];
  __shared__ __align__(16) ushort_t Bs[128 * 32];
  f32x4 acc[4][4];
#pragma unroll
  for (int i = 0; i < 4; ++i)
#pragma unroll
    for (int j = 0; j < 4; ++j) acc[i][j] = (f32x4){0.f, 0.f, 0.f, 0.f};
  int bm = blockIdx.x * 128, bn = blockIdx.y * 128;
  mfma_tile(Ab, Bb, CONVD_, INTER_, INTER_, bm, bn, HID_ - 1, As, Bs, acc);
  int t = threadIdx.x, wave = t >> 6, lane = t & 63;
  int mr = (wave >> 1) * 64, nr = (wave & 1) * 64;
  int colb = bn + nr + (lane & 15);
  int rowb = bm + mr + (lane >> 4) * 4;
#pragma unroll
  for (int i = 0; i < 4; ++i)
#pragma unroll
    for (int r = 0; r < 4; ++r) {
      int row = rowb + i * 16 + r;
#pragma unroll
      for (int j = 0; j < 4; ++j)
        C[(size_t)row * HID_ + colb + j * 16] = acc[i][j][r];
    }
}

// ---------------------------------------------------------------------------
// Causal depthwise conv (K=4) + SiLU, bf16 in -> bf16 out.
// ---------------------------------------------------------------------------
__global__ __launch_bounds__(256) void conv_silu_k(const ushort_t* __restrict__ zb,
                                                   const float* __restrict__ cw,
                                                   const float* __restrict__ cb,
                                                   ushort_t* __restrict__ xcb) {
  int idx = blockIdx.x * 256 + threadIdx.x;     // ML_ * 768 units
  int c8 = (idx % 768) * 8;
  int row = idx / 768;
  int l = row % L_;
  float a[8];
#pragma unroll
  for (int c = 0; c < 8; ++c) a[c] = cb[c8 + c];
#pragma unroll
  for (int i = 0; i < K_; ++i) {
    int ll = l - (K_ - 1) + i;
    if (ll >= 0) {
      float xv[8];
      ld_bf8(zb + (size_t)(row - (K_ - 1) + i) * ZSTR_ + INTER_ + c8, xv);
#pragma unroll
      for (int c = 0; c < 8; ++c) a[c] = fmaf(cw[(c8 + c) * K_ + i], xv[c], a[c]);
    }
  }
#pragma unroll
  for (int c = 0; c < 8; ++c) a[c] = a[c] / (1.f + __expf(-a[c]));
  st_bf8(xcb + (size_t)row * CONVD_ + c8, a);
}

// ---------------------------------------------------------------------------
// dt: softplus + cumsum per chunk.
// ---------------------------------------------------------------------------
__global__ __launch_bounds__(256) void dt_scan_k(const float* __restrict__ dtraw,
                                                 const float* __restrict__ dt_bias,
                                                 const float* __restrict__ A_log,
                                                 float* __restrict__ dtp,
                                                 float* __restrict__ dacs,
                                                 float* __restrict__ cdec) {
  int bzh = blockIdx.x;
  int h = bzh & 63, z = (bzh >> 6) & 7, b = bzh >> 9;
  int i = threadIdx.x;
  size_t row = (size_t)b * L_ + z * CS_ + i;
  float dv = dtraw[row * 64 + h] + dt_bias[h];
  float sp = (dv > 20.f) ? dv : log1pf(expf(dv));
  float v = sp * (-expf(A_log[h]));
  __shared__ float sm[256];
  sm[i] = v;
  __syncthreads();
  for (int off = 1; off < 256; off <<= 1) {
    float add = (i >= off) ? sm[i - off] : 0.f;
    __syncthreads();
    sm[i] += add;
    __syncthreads();
  }
  float cs = sm[i];
  size_t ob = ((size_t)b * H_ + h) * L_ + z * CS_ + i;
  dtp[ob] = sp;
  dacs[ob] = cs;
  if (i == CS_ - 1) cdec[bzh] = expf(cs);
}

// ---------------------------------------------------------------------------
// CB[i,j] = sum_n C[i,n]*B[j,n], lower-triangular 64x64 tiles. bf16 out.
// ---------------------------------------------------------------------------
__global__ __launch_bounds__(256) void cb_k(const ushort_t* __restrict__ xcb,
                                            ushort_t* __restrict__ CBo) {
  int jt = blockIdx.x & 3, it = blockIdx.x >> 2;
  if (jt > it) return;
  int bzg = blockIdx.y;
  int g = bzg & 7, z = (bzg >> 3) & 7, b = bzg >> 6;
  int t = threadIdx.x;
  int tx = t & 15, ty = t >> 4;
  __shared__ float CtT[64][68];
  __shared__ float BtT[64][68];
  size_t rowbase = (size_t)b * L_ + (size_t)z * CS_;
  float acc[4][4];
#pragma unroll
  for (int i = 0; i < 4; ++i)
#pragma unroll
    for (int j = 0; j < 4; ++j) acc[i][j] = 0.f;

  for (int half = 0; half < 2; ++half) {
    int nb = half * 64;
    __syncthreads();
#pragma unroll
    for (int u = 0; u < 2; ++u) {
      int idx = t + u * 256;
      int rr = idx >> 3, f = idx & 7;
      float cv[8], bv[8];
      ld_bf8(xcb + (rowbase + it * 64 + rr) * CONVD_ + INTER_ + G_ * N_ + g * N_ + nb + f * 8, cv);
      ld_bf8(xcb + (rowbase + jt * 64 + rr) * CONVD_ + INTER_ + g * N_ + nb + f * 8, bv);
#pragma unroll
      for (int c = 0; c < 8; ++c) { CtT[f * 8 + c][rr] = cv[c]; BtT[f * 8 + c][rr] = bv[c]; }
    }
    __syncthreads();
    for (int n = 0; n < 64; ++n) {
      float4 cv = *(const float4*)&CtT[n][ty * 4];
      float4 bv = *(const float4*)&BtT[n][tx * 4];
      float cc[4] = {cv.x, cv.y, cv.z, cv.w};
      float bb[4] = {bv.x, bv.y, bv.z, bv.w};
#pragma unroll
      for (int i = 0; i < 4; ++i)
#pragma unroll
        for (int j = 0; j < 4; ++j) acc[i][j] = fmaf(cc[i], bb[j], acc[i][j]);
    }
  }
  size_t cbase = ((size_t)((b * 8 + z) * 8 + g)) * (CS_ * CS_);
#pragma unroll
  for (int i = 0; i < 4; ++i) {
    int row = it * 64 + ty * 4 + i;
    ushort4 v;
    v.x = f2b(acc[i][0]); v.y = f2b(acc[i][1]); v.z = f2b(acc[i][2]); v.w = f2b(acc[i][3]);
    *(ushort4*)(CBo + cbase + (size_t)row * CS_ + jt * 64 + tx * 4) = v;
  }
}

// ---------------------------------------------------------------------------
// states (MFMA): S[p,n] = sum_j x[j,p]*w[j]*B[j,n] per (b,z,h).
// x^T and B^T staged via LDS transpose in two 128-j halves.
// ---------------------------------------------------------------------------
__global__ __launch_bounds__(256) void states_mfma(const ushort_t* __restrict__ xcb,
                                                   const float* __restrict__ dacs,
                                                   const float* __restrict__ dtp,
                                                   float* __restrict__ st) {
  int bzh = blockIdx.x;
  int h = bzh & 63, z = (bzh >> 6) & 7, b = bzh >> 9;
  int g = h >> 3;
  int t = threadIdx.x;
  int wv = t >> 6, lane = t & 63;
  int ml = lane & 15, ko = (lane >> 4) * 8;
  __shared__ float ws[256];
  __shared__ __align__(16) ushort_t Xw[64 * 136];    // (w*x)^T [p][j_half]
  __shared__ __align__(16) ushort_t Bt[128 * 136];   // B^T [n][j_half]
  size_t base = ((size_t)b * H_ + h) * L_ + z * CS_;
  float dlast = dacs[base + CS_ - 1];
  ws[t] = __expf(dlast - dacs[base + t]) * dtp[base + t];
  size_t rowbase = (size_t)b * L_ + z * CS_;
  f32x4 acc[4][2];
#pragma unroll
  for (int i = 0; i < 4; ++i) {
    acc[i][0] = (f32x4){0.f, 0.f, 0.f, 0.f};
    acc[i][1] = (f32x4){0.f, 0.f, 0.f, 0.f};
  }
  for (int half = 0; half < 2; ++half) {
    int j0 = half * 128;
    __syncthreads();
    {   // stage Xw: x[j][p]*w[j] -> Xw[p][jl]
      int jl = t >> 1, pseg = (t & 1) * 32;
      const ushort_t* xr = xcb + (rowbase + j0 + jl) * CONVD_ + h * P_ + pseg;
      float wj = ws[j0 + jl];
#pragma unroll
      for (int q = 0; q < 4; ++q) {
        float v[8];
        ld_bf8(xr + q * 8, v);
#pragma unroll
        for (int c = 0; c < 8; ++c) Xw[(pseg + q * 8 + c) * 136 + jl] = f2b(v[c] * wj);
      }
    }
    {   // stage Bt: B[j][n] -> Bt[n][jl]
      int jl = t >> 1, nseg = (t & 1) * 64;
      const ushort_t* br = xcb + (rowbase + j0 + jl) * CONVD_ + INTER_ + g * N_ + nseg;
#pragma unroll
      for (int q = 0; q < 8; ++q) {
        uint4 raw = *(const uint4*)(br + q * 8);
        const ushort_t* s = (const ushort_t*)&raw;
#pragma unroll
        for (int c = 0; c < 8; ++c) Bt[(nseg + q * 8 + c) * 136 + jl] = s[c];
      }
    }
    __syncthreads();
#pragma unroll
    for (int k0 = 0; k0 < 128; k0 += 32) {
      short8 af[4], bf2[2];
#pragma unroll
      for (int mf = 0; mf < 4; ++mf)
        af[mf] = *(const short8*)(Xw + (mf * 16 + ml) * 136 + k0 + ko);
#pragma unroll
      for (int nf = 0; nf < 2; ++nf)
        bf2[nf] = *(const short8*)(Bt + (wv * 32 + nf * 16 + ml) * 136 + k0 + ko);
#pragma unroll
      for (int mf = 0; mf < 4; ++mf)
#pragma unroll
        for (int nf = 0; nf < 2; ++nf)
          acc[mf][nf] = __builtin_amdgcn_mfma_f32_16x16x32_bf16(af[mf], bf2[nf], acc[mf][nf], 0, 0, 0);
    }
  }
  float* outp = st + ((size_t)((b * 8 + z) * H_ + h)) * (P_ * N_);
  int quad = lane >> 4;
#pragma unroll
  for (int mf = 0; mf < 4; ++mf)
#pragma unroll
    for (int nf = 0; nf < 2; ++nf) {
      int n = wv * 32 + nf * 16 + ml;
#pragma unroll
      for (int r = 0; r < 4; ++r) {
        int p = mf * 16 + quad * 4 + r;
        outp[(size_t)p * N_ + n] = acc[mf][nf][r];
      }
    }
}

// ---------------------------------------------------------------------------
// Inter-chunk exclusive scan over nc=8 chunks, IN PLACE on st.
// ---------------------------------------------------------------------------
__global__ __launch_bounds__(256) void scan_k(float* __restrict__ st,
                                              const float* __restrict__ cdec) {
  size_t idx = (size_t)blockIdx.x * 256 + threadIdx.x;
  int b = (int)(idx >> 19);            // 524288 = H_*P_*N_
  size_t rem = idx & 524287;
  int h = (int)(rem >> 13);            // 8192 = P_*N_
  float S = 0.f;
#pragma unroll
  for (int z = 0; z < NC_; ++z) {
    size_t off = (size_t)(b * 8 + z) * 524288 + rem;
    float old = st[off];
    st[off] = S;
    S = cdec[(b * 8 + z) * H_ + h] * S + old;
  }
}

// ---------------------------------------------------------------------------
// y (MFMA): Y^T[p][i] = exp(dA_i)*(prev@C^T) + M@x^T, + D*x, per (b,z,h).
// Phase A: A=prev bf16 LDS [64][136], B=C staged via global_load_lds [256][32].
// Phase B: A=x^T LDS [64][264], B=M built elementwise in LDS [256][40].
// Epilogue: transpose via LDS (Ys aliases Xs), fuse +D*x, in-place store.
// ---------------------------------------------------------------------------
__global__ __launch_bounds__(256) void y_mfma(const ushort_t* xcb,
                                              const ushort_t* __restrict__ CB,
                                              const float* __restrict__ pv,
                                              const float* __restrict__ dacs,
                                              const float* __restrict__ dtp,
                                              const float* __restrict__ Dw,
                                              ushort_t* Yx) {
  int bzh = blockIdx.x;
  int h = bzh & 63, z = (bzh >> 6) & 7, b = bzh >> 9;
  int g = h >> 3;
  int t = threadIdx.x;
  int wv = t >> 6, lane = t & 63;
  int ml = lane & 15, quad = lane >> 4, ko = quad * 8;
  __shared__ __align__(16) ushort_t Ms[256 * 40];    // Phase B M; Phase A Cs[256*32]
  __shared__ __align__(16) ushort_t XsYs[18432];     // Xs [64][264]; epilogue Ys [256][72]
  __shared__ __align__(16) ushort_t Ps[64 * 136];    // prev bf16 [p][n]
  __shared__ float dAs[256], dts[256];

  size_t rowbase = (size_t)b * L_ + z * CS_;
  {
    size_t base = ((size_t)b * H_ + h) * L_ + z * CS_;
    dAs[t] = dacs[base + t];
    dts[t] = dtp[base + t];
  }
  {   // stage prev fp32 -> bf16 Ps[p][n] (pad 136)
    int p = t >> 2, c0 = (t & 3) * 32;
    const float* pr = pv + ((size_t)((b * 8 + z) * H_ + h)) * (P_ * N_) + (size_t)p * N_ + c0;
    ushort_t* dst = Ps + p * 136 + c0;
#pragma unroll
    for (int u = 0; u < 4; ++u) {
      float4 a = *(const float4*)(pr + u * 8);
      float4 bq = *(const float4*)(pr + u * 8 + 4);
      float v[8] = {a.x, a.y, a.z, a.w, bq.x, bq.y, bq.z, bq.w};
      st_bf8(dst + u * 8, v);
    }
  }
  {   // stage Xs = x^T: read x[i=t][0..63], scatter to Xs[p][t]
    const ushort_t* xr = xcb + (rowbase + t) * CONVD_ + h * P_;
    ushort_t* Xs = XsYs;
#pragma unroll
    for (int q = 0; q < 8; ++q) {
      uint4 raw = *(const uint4*)(xr + q * 8);
      const ushort_t* s = (const ushort_t*)&raw;
#pragma unroll
      for (int c = 0; c < 8; ++c) Xs[(q * 8 + c) * 264 + t] = s[c];
    }
  }

  f32x4 acc[4][4];
#pragma unroll
  for (int i = 0; i < 4; ++i)
#pragma unroll
    for (int j = 0; j < 4; ++j) acc[i][j] = (f32x4){0.f, 0.f, 0.f, 0.f};

  // ---- Phase A: Y_off^T[p][i] = sum_n prev[p][n] * C[i][n]
  int cOff = INTER_ + G_ * N_ + g * N_;
#pragma unroll
  for (int k0 = 0; k0 < 128; k0 += 32) {
    __syncthreads();
#pragma unroll
    for (int u = 0; u < 4; ++u) {   // stage Cs tile [256][32] via global_load_lds
      int sid = u * 256 + t;
      int row = sid >> 2, kc = (sid & 3) * 8;
      gl_lds16(xcb + (rowbase + row) * CONVD_ + cOff + k0 + kc,
               Ms + (size_t)(u * 256 + wv * 64) * 8);
    }
    __syncthreads();
    short8 af[4], bf[4];
#pragma unroll
    for (int mf = 0; mf < 4; ++mf)
      af[mf] = *(const short8*)(Ps + (mf * 16 + ml) * 136 + k0 + ko);
#pragma unroll
    for (int nf = 0; nf < 4; ++nf)
      bf[nf] = *(const short8*)(Ms + (wv * 64 + nf * 16 + ml) * 32 + ko);
#pragma unroll
    for (int mf = 0; mf < 4; ++mf)
#pragma unroll
      for (int nf = 0; nf < 4; ++nf)
        acc[mf][nf] = __builtin_amdgcn_mfma_f32_16x16x32_bf16(af[mf], bf[nf], acc[mf][nf], 0, 0, 0);
  }
  // scale by exp(dA_i), i = column index
#pragma unroll
  for (int nf = 0; nf < 4; ++nf) {
    float e = __expf(dAs[wv * 64 + nf * 16 + ml]);
#pragma unroll
    for (int mf = 0; mf < 4; ++mf) {
      acc[mf][nf][0] *= e; acc[mf][nf][1] *= e;
      acc[mf][nf][2] *= e; acc[mf][nf][3] *= e;
    }
  }

  // ---- Phase B: Y_diag^T[p][i] = sum_j M[i][j] * x[j][p]
  float dAi_t = dAs[t];
  size_t cbase = ((size_t)((b * 8 + z) * 8 + g)) * (CS_ * CS_) + (size_t)t * CS_;
  const ushort_t* Xs = XsYs;
  for (int j0 = 0; j0 < 256; j0 += 32) {
    __syncthreads();
    {   // build M row i=t, cols j0..j0+31 into Ms[t][0..31] (stride 40)
      const ushort_t* cbr = CB + cbase + j0;
      ushort_t* mrow = Ms + t * 40;
#pragma unroll
      for (int q = 0; q < 4; ++q) {
        float cv[8], o[8];
        ld_bf8(cbr + q * 8, cv);
#pragma unroll
        for (int c = 0; c < 8; ++c) {
          int j = j0 + q * 8 + c;
          float m = cv[c] * __expf(dAi_t - dAs[j]) * dts[j];
          o[c] = (j <= t) ? m : 0.f;
        }
        st_bf8(mrow + q * 8, o);
      }
    }
    __syncthreads();
    short8 af[4], bf[4];
#pragma unroll
    for (int mf = 0; mf < 4; ++mf)
      af[mf] = *(const short8*)(Xs + (mf * 16 + ml) * 264 + j0 + ko);
#pragma unroll
    for (int nf = 0; nf < 4; ++nf)
      bf[nf] = *(const short8*)(Ms + (wv * 64 + nf * 16 + ml) * 40 + ko);
#pragma unroll
    for (int mf = 0; mf < 4; ++mf)
#pragma unroll
      for (int nf = 0; nf < 4; ++nf)
        acc[mf][nf] = __builtin_amdgcn_mfma_f32_16x16x32_bf16(af[mf], bf[nf], acc[mf][nf], 0, 0, 0);
  }

  // ---- Epilogue: transpose acc through LDS (Ys over Xs), +D*x, store
  __syncthreads();
  ushort_t* Ys = XsYs;   // [256][72]
#pragma unroll
  for (int mf = 0; mf < 4; ++mf)
#pragma unroll
    for (int nf = 0; nf < 4; ++nf) {
      int iw = wv * 64 + nf * 16 + ml;
      int pb = mf * 16 + quad * 4;
      uint2 pk;
      ushort_t* s = (ushort_t*)&pk;
      s[0] = f2b(acc[mf][nf][0]); s[1] = f2b(acc[mf][nf][1]);
      s[2] = f2b(acc[mf][nf][2]); s[3] = f2b(acc[mf][nf][3]);
      *(uint2*)(Ys + iw * 72 + pb) = pk;
    }
  __syncthreads();
  {
    float Dh = Dw[h];
    const ushort_t* xr = xcb + (rowbase + t) * CONVD_ + h * P_;
    ushort_t* yr = Yx + (rowbase + t) * CONVD_ + h * P_;
#pragma unroll
    for (int q = 0; q < 8; ++q) {
      float xv[8], yv[8], o[8];
      ld_bf8(xr + q * 8, xv);
      ld_bf8(Ys + t * 72 + q * 8, yv);
#pragma unroll
      for (int c = 0; c < 8; ++c) o[c] = yv[c] + Dh * xv[c];
      st_bf8(yr + q * 8, o);
    }
  }
}

// ---------------------------------------------------------------------------
// RMSNorm + silu(z) gate, in-place on xcb x-slice (stride CONVD_).
// ---------------------------------------------------------------------------
__global__ __launch_bounds__(256) void rms_gate_k(ushort_t* __restrict__ Y,
                                                  const ushort_t* __restrict__ zb,
                                                  const float* __restrict__ nw) {
  int row = blockIdx.x;
  int t = threadIdx.x;
  ushort_t* y = Y + (size_t)row * CONVD_;
  const ushort_t* zp = zb + (size_t)row * ZSTR_;
  float v[2][8];
  float s = 0.f;
#pragma unroll
  for (int u = 0; u < 2; ++u) {
    ld_bf8(y + u * 2048 + t * 8, v[u]);
#pragma unroll
    for (int c = 0; c < 8; ++c) s += v[u][c] * v[u][c];
  }
#pragma unroll
  for (int off = 32; off > 0; off >>= 1) s += __shfl_down(s, off);
  __shared__ float red[4];
  if ((t & 63) == 0) red[t >> 6] = s;
  __syncthreads();
  float tot = red[0] + red[1] + red[2] + red[3];
  float rstd = rsqrtf(tot * (1.f / INTER_) + EPS_);
#pragma unroll
  for (int u = 0; u < 2; ++u) {
    int c0 = u * 2048 + t * 8;
    float zv[8], o[8];
    ld_bf8(zp + c0, zv);
    float4 w0 = *(const float4*)(nw + c0);
    float4 w1 = *(const float4*)(nw + c0 + 4);
    float wv[8] = {w0.x, w0.y, w0.z, w0.w, w1.x, w1.y, w1.z, w1.w};
#pragma unroll
    for (int c = 0; c < 8; ++c)
      o[c] = wv[c] * v[u][c] * rstd * (zv[c] / (1.f + __expf(-zv[c])));
    st_bf8(y + c0, o);
  }
}

// ---------------------------------------------------------------------------
extern "C" void kernel_launch(void* const* d_in, const int* in_sizes, int n_in,
                              void* d_out, int out_size, void* d_ws, size_t ws_size,
                              hipStream_t stream) {
  const float* hs    = (const float*)d_in[0];
  const float* w_in  = (const float*)d_in[1];
  const float* cw    = (const float*)d_in[2];
  const float* cb    = (const float*)d_in[3];
  const float* dtb   = (const float*)d_in[4];
  const float* alog  = (const float*)d_in[5];
  const float* Dw    = (const float*)d_in[6];
  const float* nw    = (const float*)d_in[7];
  const float* w_out = (const float*)d_in[8];
  float* out = (float*)d_out;

  // Workspace layout (~187.3 MiB), regions R1/R2 time-aliased:
  //   R1: hsb [cast1,gemm1] -> cbuf [cb_k..y] -> w_outb [cast2,gemm2]
  //   R2: w_inb [cast1,gemm1] -> st [states..y]
  char* base = (char*)d_ws;
  ushort_t* zb    = (ushort_t*)(base);                         //  83,886,080 B
  ushort_t* xcb   = (ushort_t*)(base + 83886080);              //  50,331,648 B
  float*    dtraw = (float*)(base + 134217728);                //   1,048,576 B
  float*    dtp   = (float*)(base + 135266304);                //   1,048,576 B
  float*    dacs  = (float*)(base + 136314880);                //   1,048,576 B
  float*    cdec  = (float*)(base + 137363456);                //       4,096 B
  char*     R1    = base + 137367552;                          //  16,777,216 B
  char*     R2    = base + 154144768;                          //  42,205,184 B
  ushort_t* hsb    = (ushort_t*)R1;
  ushort_t* cbuf   = (ushort_t*)R1;
  ushort_t* w_outb = (ushort_t*)R1;
  ushort_t* w_inb  = (ushort_t*)R2;
  float*    st     = (float*)R2;

  cast1_k<<<14400, 256, 0, stream>>>(hs, w_in, hsb, w_inb);
  gemm1_mfma<<<dim3(32, 81), 256, 0, stream>>>(hsb, w_inb, zb, dtraw);
  conv_silu_k<<<(ML_ * (CONVD_ / 8)) / 256, 256, 0, stream>>>(zb, cw, cb, xcb);
  dt_scan_k<<<B_ * NC_ * H_, 256, 0, stream>>>(dtraw, dtb, alog, dtp, dacs, cdec);
  cb_k<<<dim3(16, B_ * NC_ * G_), 256, 0, stream>>>(xcb, cbuf);
  states_mfma<<<B_ * NC_ * H_, 256, 0, stream>>>(xcb, dacs, dtp, st);
  scan_k<<<(B_ * H_ * P_ * N_) / 256, 256, 0, stream>>>(st, cdec);
  y_mfma<<<B_ * NC_ * H_, 256, 0, stream>>>(xcb, cbuf, st, dacs, dtp, Dw, xcb);
  rms_gate_k<<<ML_, 256, 0, stream>>>(xcb, zb, nw);
  cast2_k<<<4096, 256, 0, stream>>>(w_out, w_outb);
  gemm2_mfma<<<dim3(32, 16), 256, 0, stream>>>(xcb, w_outb, out);
}